// Round 6
// baseline (402.060 us; speedup 1.0000x reference)
//
#include <hip/hip_runtime.h>
#include <math.h>

#define HID 128
#define NB 128     // one block per k
#define NT 512     // 8 waves: (ihalf 0..1) x (jq 0..3)

typedef __attribute__((ext_vector_type(8))) short short8;
typedef __attribute__((ext_vector_type(4))) short short4v;
typedef __attribute__((ext_vector_type(4))) float f32x4;

__device__ __forceinline__ unsigned short f2bf(float f) {   // fp32 -> bf16 RNE
    unsigned int u = __float_as_uint(f);
    u += 0x7FFFu + ((u >> 16) & 1u);
    return (unsigned short)(u >> 16);
}
__device__ __forceinline__ float bf2f(unsigned short s) {
    return __uint_as_float(((unsigned int)s) << 16);
}
__device__ __forceinline__ void pack_hilo(float a, float c, unsigned& h, unsigned& l) {
    const unsigned short ha = f2bf(a), hc = f2bf(c);
    const unsigned short la = f2bf(a - bf2f(ha)), lc = f2bf(c - bf2f(hc));
    h = (unsigned)ha | ((unsigned)hc << 16);
    l = (unsigned)la | ((unsigned)lc << 16);
}

// device-scope grid barrier (count+generation); agent fences handle cross-XCD vis.
__device__ __forceinline__ void gridbar(unsigned* bar) {
    __syncthreads();
    if (threadIdx.x == 0) {
        __threadfence();
        unsigned* cnt = bar;
        unsigned* gen = bar + 1;
        unsigned g = __hip_atomic_load(gen, __ATOMIC_RELAXED, __HIP_MEMORY_SCOPE_AGENT);
        unsigned a = __hip_atomic_fetch_add(cnt, 1u, __ATOMIC_ACQ_REL, __HIP_MEMORY_SCOPE_AGENT);
        if (a == (unsigned)(NB - 1)) {
            __hip_atomic_store(cnt, 0u, __ATOMIC_RELAXED, __HIP_MEMORY_SCOPE_AGENT);
            __hip_atomic_store(gen, g + 1u, __ATOMIC_RELEASE, __HIP_MEMORY_SCOPE_AGENT);
        } else {
            while (__hip_atomic_load(gen, __ATOMIC_ACQUIRE, __HIP_MEMORY_SCOPE_AGENT) == g)
                __builtin_amdgcn_s_sleep(8);
        }
        __threadfence();
    }
    __syncthreads();
}

// Persistent RNTN: V resident in VGPRs (hi/lo bf16 shards), 9 levels + output fused.
// Wave (ihalf,jq) shard: V[k][ihalf*128 +: 128][jq*64 +: 64] as 8x2 MFMA frag pairs.
__global__ __launch_bounds__(NT, 2)
void rntn_persistent(const float* __restrict__ embed, const float* __restrict__ V,
                     const float* __restrict__ W, const float* __restrict__ b,
                     const float* __restrict__ Woutw, const float* __restrict__ Woutb,
                     const int* __restrict__ word_ids, const int* __restrict__ left,
                     const int* __restrict__ right, float* __restrict__ H,
                     unsigned* bar, float* __restrict__ out)
{
    __shared__ __align__(16) unsigned short Xh[32 * 256];  // 32-node tile, XOR-swizzled
    __shared__ __align__(16) unsigned short Xl[32 * 256];
    __shared__ float qred[256];

    const int t = threadIdx.x;
    const int k = blockIdx.x;          // 0..127
    const int w = t >> 6;              // wave 0..7
    const int ihalf = w >> 2;          // i-half
    const int jq = w & 3;              // j-quarter
    const int lane = t & 63;
    const int colsel = lane & 15;
    const int kg = lane >> 4;

    // ---- V shard -> registers (hi/lo split on the fly; 128 VGPRs) ----
    short8 vfh[8][2], vfl[8][2];
    {
        const float* Vk = V + ((size_t)k << 16) + (size_t)ihalf * 128 * 256 + jq * 64;
#pragma unroll
        for (int ig = 0; ig < 8; ++ig) {
#pragma unroll
            for (int ks = 0; ks < 2; ++ks) {
                const float* p = Vk + (size_t)(ig * 16 + colsel) * 256 + ks * 32 + kg * 8;
                const float4 s0 = *(const float4*)p;
                const float4 s1 = *(const float4*)(p + 4);
                uint4 ph, pl;
                pack_hilo(s0.x, s0.y, ph.x, pl.x);
                pack_hilo(s0.z, s0.w, ph.y, pl.y);
                pack_hilo(s1.x, s1.y, ph.z, pl.z);
                pack_hilo(s1.z, s1.w, ph.w, pl.w);
                vfh[ig][ks] = *(short8*)&ph;
                vfl[ig][ks] = *(short8*)&pl;
            }
        }
    }
    // ---- W column (acc-init values, identical for all node-cols) ----
    f32x4 wk[8];
#pragma unroll
    for (int ig = 0; ig < 8; ++ig) {
        const int i0 = ihalf * 128 + ig * 16 + kg * 4;
#pragma unroll
        for (int r = 0; r < 4; ++r) wk[ig][r] = W[(size_t)(i0 + r) * HID + k];
    }
    const float bk = b[k];

    int ls = 512, nn = 256;
#pragma unroll 1
    for (int L = 0; L < 9; ++L) {
        const int ntiles = (nn + 31) >> 5;
#pragma unroll 1
        for (int tile = 0; tile < ntiles; ++tile) {
            const int nbase = tile << 5;
            // ---- stage 32 nodes of X = concat(H[l],H[r]) as hi/lo bf16 ----
            for (int idx = t; idx < 1024; idx += NT) {
                const int row = idx >> 5, ch = idx & 31, i0 = ch * 8;
                uint4 ph = make_uint4(0u, 0u, 0u, 0u), pl = ph;
                const int n = nbase + row;
                if (n < nn) {
                    const int node = ls + n;
                    const int child = (i0 < HID) ? left[node] : right[node];
                    const float* src = (child < 512)
                        ? (embed + (size_t)word_ids[child] * HID)   // leaf: direct embed
                        : (H + (size_t)child * HID);
                    const float4 x0 = *(const float4*)(src + (i0 & 127));
                    const float4 x1 = *(const float4*)(src + (i0 & 127) + 4);
                    pack_hilo(x0.x, x0.y, ph.x, pl.x);
                    pack_hilo(x0.z, x0.w, ph.y, pl.y);
                    pack_hilo(x1.x, x1.y, ph.z, pl.z);
                    pack_hilo(x1.z, x1.w, ph.w, pl.w);
                }
                const int ad = (row * 256 + i0) ^ ((row & 7) << 3);
                *(uint4*)&Xh[ad] = ph;
                *(uint4*)&Xl[ad] = pl;
            }
            __syncthreads();

#pragma unroll
            for (int g = 0; g < 2; ++g) {
                const int brow = g * 16 + colsel;
                short8 bh[2], bl[2];
#pragma unroll
                for (int ks = 0; ks < 2; ++ks) {
                    const int ad = (brow * 256 + jq * 64 + ks * 32 + kg * 8) ^ ((brow & 7) << 3);
                    bh[ks] = *(const short8*)&Xh[ad];
                    bl[ks] = *(const short8*)&Xl[ad];
                }
                f32x4 acc[8];
#pragma unroll
                for (int ig = 0; ig < 8; ++ig)
                    acc[ig] = (jq == 0) ? wk[ig] : (f32x4){0.f, 0.f, 0.f, 0.f};
#pragma unroll
                for (int ks = 0; ks < 2; ++ks) {
#pragma unroll
                    for (int ig = 0; ig < 8; ++ig) {
                        acc[ig] = __builtin_amdgcn_mfma_f32_16x16x32_bf16(vfh[ig][ks], bh[ks], acc[ig], 0, 0, 0);
                        acc[ig] = __builtin_amdgcn_mfma_f32_16x16x32_bf16(vfl[ig][ks], bh[ks], acc[ig], 0, 0, 0);
                        acc[ig] = __builtin_amdgcn_mfma_f32_16x16x32_bf16(vfh[ig][ks], bl[ks], acc[ig], 0, 0, 0);
                    }
                }
                // epilogue: q_partial(n=brow) = sum_{i in shard's ihalf} X[n,i]*acc
                float q = 0.f;
#pragma unroll
                for (int ig = 0; ig < 8; ++ig) {
                    const int i0 = ihalf * 128 + ig * 16 + kg * 4;
                    const int ad = (brow * 256 + i0) ^ ((brow & 7) << 3);
                    const short4v h4 = *(const short4v*)&Xh[ad];
                    const short4v l4 = *(const short4v*)&Xl[ad];
#pragma unroll
                    for (int r = 0; r < 4; ++r) {
                        const float xv = bf2f((unsigned short)h4[r]) + bf2f((unsigned short)l4[r]);
                        q = fmaf(xv, acc[ig][r], q);
                    }
                }
                q += __shfl_xor(q, 16, 64);
                q += __shfl_xor(q, 32, 64);
                if (kg == 0) qred[w * 32 + g * 16 + colsel] = q;
            }
            __syncthreads();
            if (t < 32) {
                const int n = nbase + t;
                if (n < nn) {
                    float s = bk;
#pragma unroll
                    for (int ww = 0; ww < 8; ++ww) s += qred[ww * 32 + t];
                    H[(size_t)(ls + n) * HID + k] = tanhf(s);
                }
            }
            // next tile's staging writes Xh/Xl only; qred reused after post-stage sync. Safe.
        }
        gridbar(bar);          // level l+1 (and out phase) reads this level's H
        ls += nn;
        nn >>= 1;
    }

    // ---- fused output: logits + log_softmax, one wave per node ----
    const int node = k * 8 + w;
    if (node < 1023) {
        const float* hrow = (node < 512)
            ? (embed + (size_t)word_ids[node] * HID)
            : (H + (size_t)node * HID);
        const float h0 = hrow[lane];
        const float h1 = hrow[64 + lane];
        float p[5];
#pragma unroll
        for (int o = 0; o < 5; ++o) {
            p[o] = h0 * Woutw[o * HID + lane] + h1 * Woutw[o * HID + 64 + lane];
#pragma unroll
            for (int m = 1; m < 64; m <<= 1) p[o] += __shfl_xor(p[o], m, 64);
        }
        if (lane == 0) {
            float lg[5], mx = -1e30f;
#pragma unroll
            for (int o = 0; o < 5; ++o) { lg[o] = p[o] + Woutb[o]; mx = fmaxf(mx, lg[o]); }
            float s = 0.f;
#pragma unroll
            for (int o = 0; o < 5; ++o) s += expf(lg[o] - mx);
            const float lse = mx + logf(s);
#pragma unroll
            for (int o = 0; o < 5; ++o) out[(size_t)node * 5 + o] = lg[o] - lse;
        }
    }
}

extern "C" void kernel_launch(void* const* d_in, const int* in_sizes, int n_in,
                              void* d_out, int out_size, void* d_ws, size_t ws_size,
                              hipStream_t stream) {
    const float* embed   = (const float*)d_in[0];
    const float* V       = (const float*)d_in[1];
    const float* W       = (const float*)d_in[2];
    const float* b       = (const float*)d_in[3];
    const float* Woutw   = (const float*)d_in[4];
    const float* Woutb   = (const float*)d_in[5];
    const int*   wordids = (const int*)d_in[6];
    const int*   left    = (const int*)d_in[7];
    const int*   right   = (const int*)d_in[8];
    // d_in[9] (is_leaf) unused: balanced tree => leaves are exactly t<512.

    float*    H   = (float*)d_ws;                          // 1023 x 128 fp32 (leaves unused)
    unsigned* bar = (unsigned*)((char*)d_ws + (1 << 20));  // barrier counters
    float*    out = (float*)d_out;

    hipMemsetAsync(bar, 0, 8, stream);

    void* args[] = {(void*)&embed, (void*)&V, (void*)&W, (void*)&b,
                    (void*)&Woutw, (void*)&Woutb, (void*)&wordids,
                    (void*)&left, (void*)&right, (void*)&H, (void*)&bar, (void*)&out};
    hipLaunchCooperativeKernel((void*)rntn_persistent, dim3(NB), dim3(NT),
                               args, 0, stream);
}